// Round 9
// baseline (80.381 us; speedup 1.0000x reference)
//
#include <hip/hip_runtime.h>
#include <cstdint>

#define M_DIM 2048
#define K_DIM 4096
#define N_DIM 4096

#define BM 128
#define BN 128
#define BK 128                       // i8 elements = bytes per K-tile row
#define KT (K_DIM / BK)              // 32 K-tiles
#define A_TILE_BYTES (BM * BK)       // 16 KiB
#define B_TILE_BYTES (BN * BK)       // 16 KiB
#define TILE_BYTES (A_TILE_BYTES + B_TILE_BYTES)  // 32 KiB
#define NBUF 2
#define LDS_BYTES (NBUF * TILE_BYTES)             // 64 KiB -> 2 blocks/CU

typedef __attribute__((ext_vector_type(4))) int i32x4;

__device__ __forceinline__ void gload_lds16(const void* g, void* l) {
  __builtin_amdgcn_global_load_lds(
      (__attribute__((address_space(1))) void*)(g),
      (__attribute__((address_space(3))) void*)(l), 16, 0, 0);
}

// ============================================================================
// K1: fused reducers — no global atomics.
// ============================================================================
__global__ void fused_reduce_kernel(const float* __restrict__ x,
                                    const float* __restrict__ rw,
                                    const float* __restrict__ w,
                                    float* __restrict__ invrms,
                                    float* __restrict__ rowmax,
                                    double* __restrict__ partials) {
  const int tid = threadIdx.x;
  __shared__ double red[4];
  __shared__ float redf[4];
  __shared__ float sInv;

  if (blockIdx.x < 2048) {
    const int row = blockIdx.x;
    const float4* xr = (const float4*)(x + (size_t)row * K_DIM);
    const float4* wr = (const float4*)rw;
    float4 xv[4];
    double ss = 0.0;
#pragma unroll
    for (int i = 0; i < 4; i++) {
      xv[i] = xr[i * 256 + tid];
      ss += (double)xv[i].x * xv[i].x + (double)xv[i].y * xv[i].y +
            (double)xv[i].z * xv[i].z + (double)xv[i].w * xv[i].w;
    }
    for (int off = 32; off; off >>= 1) ss += __shfl_down(ss, off);
    if ((tid & 63) == 0) red[tid >> 6] = ss;
    __syncthreads();
    if (tid == 0) {
      double t = red[0] + red[1] + red[2] + red[3];
      sInv = (float)(1.0 / sqrt(t * (1.0 / (double)K_DIM) + 1e-6));
    }
    __syncthreads();
    const float inv = sInv;
    if (tid == 0) invrms[row] = inv;

    float amax = 0.f;
#pragma unroll
    for (int i = 0; i < 4; i++) {
      float4 wv = wr[i * 256 + tid];
      amax = fmaxf(amax, fabsf((xv[i].x * inv) * wv.x));
      amax = fmaxf(amax, fabsf((xv[i].y * inv) * wv.y));
      amax = fmaxf(amax, fabsf((xv[i].z * inv) * wv.z));
      amax = fmaxf(amax, fabsf((xv[i].w * inv) * wv.w));
    }
    for (int off = 32; off; off >>= 1) amax = fmaxf(amax, __shfl_down(amax, off));
    if ((tid & 63) == 0) redf[tid >> 6] = amax;
    __syncthreads();
    if (tid == 0)
      rowmax[row] = fmaxf(fmaxf(redf[0], redf[1]), fmaxf(redf[2], redf[3]));
  } else {
    const int bid = blockIdx.x - 2048;
    const float4* w4 = (const float4*)w;
    const size_t base = (size_t)bid * 2048;
    double s = 0.0;
#pragma unroll
    for (int i = 0; i < 8; i++) {
      float4 v = w4[base + i * 256 + tid];
      s += (double)((fabsf(v.x) + fabsf(v.y)) + (fabsf(v.z) + fabsf(v.w)));
    }
    for (int off = 32; off; off >>= 1) s += __shfl_down(s, off);
    if ((tid & 63) == 0) red[tid >> 6] = s;
    __syncthreads();
    if (tid == 0) partials[bid] = red[0] + red[1] + red[2] + red[3];
  }
}

// ============================================================================
// K2: single-block scale finalizer -> scales = {a_scale, b_scale, dq}
// ============================================================================
__global__ void scales_kernel(const float* __restrict__ rowmax,
                              const double* __restrict__ partials,
                              float* __restrict__ scales) {
  const int tid = threadIdx.x;
  float m = 0.f;
  double s = 0.0;
#pragma unroll
  for (int i = 0; i < 8; i++) {
    m = fmaxf(m, rowmax[i * 256 + tid]);
    s += partials[i * 256 + tid];
  }
  for (int off = 32; off; off >>= 1) {
    m = fmaxf(m, __shfl_down(m, off));
    s += __shfl_down(s, off);
  }
  __shared__ float redf[4];
  __shared__ double red[4];
  if ((tid & 63) == 0) { redf[tid >> 6] = m; red[tid >> 6] = s; }
  __syncthreads();
  if (tid == 0) {
    float amax = fmaxf(fmaxf(redf[0], redf[1]), fmaxf(redf[2], redf[3]));
    double wsum = red[0] + red[1] + red[2] + red[3];
    float as = 127.0f / fmaxf(amax, 1e-5f);
    float mean_f = (float)(wsum * (1.0 / 16777216.0));
    float bs = 1.0f / fmaxf(mean_f, 1e-5f);
    scales[0] = as;
    scales[1] = bs;
    scales[2] = 1.0f / (as * bs);
  }
}

// ============================================================================
// K3: fused quantizers (A rows int8; 64x64 ternary W tiles transposed).
// ============================================================================
__global__ void fused_quant_kernel(const float* __restrict__ x,
                                   const float* __restrict__ rw,
                                   const float* __restrict__ invrms,
                                   const float* __restrict__ scales,
                                   const float* __restrict__ w,
                                   char* __restrict__ Aq,
                                   char* __restrict__ Bt) {
  const int tid = threadIdx.x;
  if (blockIdx.x < 2048) {
    const int row = blockIdx.x;
    const float inv = invrms[row];
    const float as = scales[0];
    const float4* xr = (const float4*)(x + (size_t)row * K_DIM);
    const float4* wr = (const float4*)rw;
    union { char c[16]; int4 v; } o;
#pragma unroll
    for (int i = 0; i < 4; i++) {
      float4 xv = xr[tid * 4 + i];
      float4 wv = wr[tid * 4 + i];
      float t0 = (xv.x * inv) * wv.x;
      float t1 = (xv.y * inv) * wv.y;
      float t2 = (xv.z * inv) * wv.z;
      float t3 = (xv.w * inv) * wv.w;
      o.c[i * 4 + 0] = (char)(int)fminf(fmaxf(rintf(t0 * as), -128.f), 127.f);
      o.c[i * 4 + 1] = (char)(int)fminf(fmaxf(rintf(t1 * as), -128.f), 127.f);
      o.c[i * 4 + 2] = (char)(int)fminf(fmaxf(rintf(t2 * as), -128.f), 127.f);
      o.c[i * 4 + 3] = (char)(int)fminf(fmaxf(rintf(t3 * as), -128.f), 127.f);
    }
    *(int4*)(Aq + (size_t)row * K_DIM + tid * 16) = o.v;
  } else {
    __shared__ float lds[64][68];
    const int tile = blockIdx.x - 2048;
    const int n0 = (tile & 63) * 64;
    const int k0 = (tile >> 6) * 64;
    const float bs = scales[1];
#pragma unroll
    for (int i = 0; i < 4; i++) {
      const int id = i * 256 + tid;
      const int r = id >> 4;
      const int c4 = (id & 15) * 4;
      float4 v = *(const float4*)(w + (size_t)(k0 + r) * N_DIM + n0 + c4);
      lds[c4 + 0][r] = fminf(fmaxf(rintf(v.x * bs), -1.f), 1.f);
      lds[c4 + 1][r] = fminf(fmaxf(rintf(v.y * bs), -1.f), 1.f);
      lds[c4 + 2][r] = fminf(fmaxf(rintf(v.z * bs), -1.f), 1.f);
      lds[c4 + 3][r] = fminf(fmaxf(rintf(v.w * bs), -1.f), 1.f);
    }
    __syncthreads();
    const int rn = tid >> 2;
    const int kg = (tid & 3) * 16;
    union { char c[16]; int4 v; } o;
#pragma unroll
    for (int j = 0; j < 16; j++) o.c[j] = (char)(int)lds[rn][kg + j];
    *(int4*)(Bt + (size_t)(n0 + rn) * K_DIM + k0 + kg) = o.v;
  }
}

// ============================================================================
// K4: i8 GEMM tuned for CROSS-BLOCK overlap (m114 mechanism): BM=BN=BK=128,
//     128 thr / 2 waves per block (wave-tile 128x64), grid 512 = 2 blocks/CU,
//     NBUF=2 (64 KB LDS/block -> both blocks resident). Blocks share no
//     barrier, so one block's LDS phases hide under the other's MFMA phases.
//     Per tile: barrier -> issue stage(t+1) (16 gload_lds) -> vmcnt(16)
//     (never 0 until last tile) -> 24 frag ds_reads in 2 lgkm-split ks-phases
//     -> 2x32 MFMA. Barrier BEFORE stage-issue fences t-1 reads vs buffer
//     reuse. XOR-swizzled LDS (inverse-swizzled global source).
// ============================================================================
__global__ void __launch_bounds__(128, 1)
gemm_kernel(const char* __restrict__ Aq, const char* __restrict__ Bt,
            float* __restrict__ out, const float* __restrict__ scales) {
  extern __shared__ char lds[];
  const int tid = threadIdx.x;
  const int lane = tid & 63;
  const int wv = tid >> 6;        // 0..1 -> 64-col band of 128
  // XCD-bijective swizzle (512 % 8 == 0): contiguous 64-block chunks per XCD
  const int flat = blockIdx.x;
  const int swzb = (flat & 7) * 64 + (flat >> 3);
  const int bx = swzb & 31;       // N block (32)
  const int by = swzb >> 5;       // M block (16)
  const int brow = by * BM;
  const int bcol = bx * BN;

  i32x4 acc[8][4];
#pragma unroll
  for (int m = 0; m < 8; m++)
#pragma unroll
    for (int n = 0; n < 4; n++) acc[m][n] = {0, 0, 0, 0};

  // staging: op s covers 8 rows: row = s*16 + wv*8 + (lane>>3), col16 = lane&7
  // row&7 == lane>>3 -> inverse-swizzled source col16 = (lane&7) ^ (lane>>3)
  const int sRow8 = lane >> 3;
  const int srcColB = ((lane & 7) ^ sRow8) * 16;

#define STAGE_A(kt, bi, s)                                                        \
  gload_lds16(Aq + (size_t)(brow + (s)*16 + wv * 8 + sRow8) * K_DIM +             \
                  (kt)*BK + srcColB,                                              \
              lds + (bi)*TILE_BYTES + ((s)*16 + wv * 8) * 128 + lane * 16)
#define STAGE_B(kt, bi, s)                                                        \
  gload_lds16(Bt + (size_t)(bcol + (s)*16 + wv * 8 + sRow8) * K_DIM +             \
                  (kt)*BK + srcColB,                                              \
              lds + (bi)*TILE_BYTES + A_TILE_BYTES + ((s)*16 + wv * 8) * 128 +    \
                  lane * 16)

  // prologue: stage tile 0 into buf 0 (16 ops/wave)
#pragma unroll
  for (int s = 0; s < 8; s++) STAGE_A(0, 0, s);
#pragma unroll
  for (int s = 0; s < 8; s++) STAGE_B(0, 0, s);

  // fragment geometry (16x16x64): lane l -> row l&15, 16B col (l>>4) within a
  // 64-elem K-slice; swizzled col16' = col16 ^ (row&7), row&7 = lane&7.
  const int aBase = (lane & 15) * BK;                 // A rows: m*16 + (lane&15)
  const int bBase = (wv * 64 + (lane & 15)) * BK;     // B cols: band + n*16 + ..
  const int swz0 = ((0 + (lane >> 4)) ^ (lane & 7)) * 16;  // ks=0
  const int swz1 = ((4 + (lane >> 4)) ^ (lane & 7)) * 16;  // ks=1

  for (int t = 0; t < KT; ++t) {
    const int bi = t & 1;
    const char* bufA = lds + bi * TILE_BYTES;
    const char* bufB = bufA + A_TILE_BYTES;

    __builtin_amdgcn_s_barrier();   // all waves done reading buf[(t+1)&1]
    __builtin_amdgcn_sched_barrier(0);
    if (t + 1 < KT) {               // stage t+1 into the other buffer
      const int si = (t + 1) & 1;
#pragma unroll
      for (int s = 0; s < 8; s++) STAGE_A(t + 1, si, s);
#pragma unroll
      for (int s = 0; s < 8; s++) STAGE_B(t + 1, si, s);
      asm volatile("s_waitcnt vmcnt(16)" ::: "memory");  // tile t landed
    } else {
      asm volatile("s_waitcnt vmcnt(0)" ::: "memory");
    }
    __builtin_amdgcn_sched_barrier(0);

    i32x4 a0[8], a1[8], b0[4], b1[4];
    // phase-1 reads (ks=0): A m0..7 + B n0..3
#pragma unroll
    for (int m = 0; m < 8; m++) a0[m] = *(const i32x4*)(bufA + aBase + m * 2048 + swz0);
#pragma unroll
    for (int n = 0; n < 4; n++) b0[n] = *(const i32x4*)(bufB + bBase + n * 2048 + swz0);
    __builtin_amdgcn_sched_barrier(0);
    // phase-2 reads (ks=1)
#pragma unroll
    for (int m = 0; m < 8; m++) a1[m] = *(const i32x4*)(bufA + aBase + m * 2048 + swz1);
#pragma unroll
    for (int n = 0; n < 4; n++) b1[n] = *(const i32x4*)(bufB + bBase + n * 2048 + swz1);

    asm volatile("s_waitcnt lgkmcnt(12)" ::: "memory");  // phase-1's 12 retired
    __builtin_amdgcn_sched_barrier(0);
    __builtin_amdgcn_s_setprio(1);
#pragma unroll
    for (int m = 0; m < 8; m++)
#pragma unroll
      for (int n = 0; n < 4; n++)
        acc[m][n] = __builtin_amdgcn_mfma_i32_16x16x64_i8(a0[m], b0[n], acc[m][n], 0, 0, 0);
    __builtin_amdgcn_s_setprio(0);

    asm volatile("s_waitcnt lgkmcnt(0)" ::: "memory");   // phase-2 retired
    __builtin_amdgcn_sched_barrier(0);
    __builtin_amdgcn_s_setprio(1);
#pragma unroll
    for (int m = 0; m < 8; m++)
#pragma unroll
      for (int n = 0; n < 4; n++)
        acc[m][n] = __builtin_amdgcn_mfma_i32_16x16x64_i8(a1[m], b1[n], acc[m][n], 0, 0, 0);
    __builtin_amdgcn_s_setprio(0);
  }
#undef STAGE_A
#undef STAGE_B

  const float dq = scales[2];
#pragma unroll
  for (int m = 0; m < 8; m++) {
#pragma unroll
    for (int n = 0; n < 4; n++) {
      const int row = m * 16 + (lane >> 4) * 4;
      const int col = wv * 64 + n * 16 + (lane & 15);
#pragma unroll
      for (int j = 0; j < 4; j++) {
        out[(size_t)(brow + row + j) * N_DIM + bcol + col] = (float)acc[m][n][j] * dq;
      }
    }
  }
}

// ============================================================================
extern "C" void kernel_launch(void* const* d_in, const int* in_sizes, int n_in,
                              void* d_out, int out_size, void* d_ws, size_t ws_size,
                              hipStream_t stream) {
  const float* x      = (const float*)d_in[0];   // [1,2048,4096]
  const float* weight = (const float*)d_in[1];   // [4096,4096]
  const float* rms_w  = (const float*)d_in[2];   // [4096]
  float* out = (float*)d_out;

  uint8_t* ws = (uint8_t*)d_ws;
  float* scales    = (float*)(ws + 0);                     // 3 floats
  float* invrms    = (float*)(ws + 64);                    // 8KB
  float* rowmax    = (float*)(ws + 64 + 8192);             // 8KB
  double* partials = (double*)(ws + 64 + 16384);           // 16KB
  char* Aq = (char*)(ws + 65536);                          // 8MB
  char* Bt = (char*)(ws + 65536 + (size_t)M_DIM * K_DIM);  // 16MB

  (void)hipFuncSetAttribute((const void*)gemm_kernel,
                            hipFuncAttributeMaxDynamicSharedMemorySize, LDS_BYTES);

  fused_reduce_kernel<<<4096, 256, 0, stream>>>(x, rms_w, weight, invrms, rowmax, partials);
  scales_kernel<<<1, 256, 0, stream>>>(rowmax, partials, scales);
  fused_quant_kernel<<<6144, 256, 0, stream>>>(x, rms_w, invrms, scales, weight, Aq, Bt);
  gemm_kernel<<<512, 128, LDS_BYTES, stream>>>(Aq, Bt, out, scales);
}

// Round 10
// 74.271 us; speedup vs baseline: 1.0823x; 1.0823x over previous
//
#include <hip/hip_runtime.h>
#include <cstdint>

#define M_DIM 2048
#define K_DIM 4096
#define N_DIM 4096

#define BM 256
#define BN 128
#define BK 128                       // i8 elements = bytes per K-tile row
#define KT (K_DIM / BK)              // 32 K-tiles
#define A_TILE_BYTES (BM * BK)       // 32 KiB
#define B_TILE_BYTES (BN * BK)       // 16 KiB
#define TILE_BYTES (A_TILE_BYTES + B_TILE_BYTES)  // 48 KiB
#define NBUF 3
#define LDS_BYTES (NBUF * TILE_BYTES)             // 144 KiB

typedef __attribute__((ext_vector_type(4))) int i32x4;

__device__ __forceinline__ void gload_lds16(const void* g, void* l) {
  __builtin_amdgcn_global_load_lds(
      (__attribute__((address_space(1))) void*)(g),
      (__attribute__((address_space(3))) void*)(l), 16, 0, 0);
}

// ============================================================================
// K1: fused reducers — no global atomics.
//     blocks [0,2048):   per-row RMS -> invrms[row]; per-row absmax of xn
//                        -> rowmax[row] (exclusive slot, plain store).
//     blocks [2048,4096): |W| partial sums -> partials[bid] (double tree).
// ============================================================================
__global__ void fused_reduce_kernel(const float* __restrict__ x,
                                    const float* __restrict__ rw,
                                    const float* __restrict__ w,
                                    float* __restrict__ invrms,
                                    float* __restrict__ rowmax,
                                    double* __restrict__ partials) {
  const int tid = threadIdx.x;
  __shared__ double red[4];
  __shared__ float redf[4];
  __shared__ float sInv;

  if (blockIdx.x < 2048) {
    const int row = blockIdx.x;
    const float4* xr = (const float4*)(x + (size_t)row * K_DIM);
    const float4* wr = (const float4*)rw;
    float4 xv[4];
    double ss = 0.0;
#pragma unroll
    for (int i = 0; i < 4; i++) {
      xv[i] = xr[i * 256 + tid];
      ss += (double)xv[i].x * xv[i].x + (double)xv[i].y * xv[i].y +
            (double)xv[i].z * xv[i].z + (double)xv[i].w * xv[i].w;
    }
    for (int off = 32; off; off >>= 1) ss += __shfl_down(ss, off);
    if ((tid & 63) == 0) red[tid >> 6] = ss;
    __syncthreads();
    if (tid == 0) {
      double t = red[0] + red[1] + red[2] + red[3];
      sInv = (float)(1.0 / sqrt(t * (1.0 / (double)K_DIM) + 1e-6));
    }
    __syncthreads();
    const float inv = sInv;
    if (tid == 0) invrms[row] = inv;

    float amax = 0.f;
#pragma unroll
    for (int i = 0; i < 4; i++) {
      float4 wv = wr[i * 256 + tid];
      amax = fmaxf(amax, fabsf((xv[i].x * inv) * wv.x));
      amax = fmaxf(amax, fabsf((xv[i].y * inv) * wv.y));
      amax = fmaxf(amax, fabsf((xv[i].z * inv) * wv.z));
      amax = fmaxf(amax, fabsf((xv[i].w * inv) * wv.w));
    }
    for (int off = 32; off; off >>= 1) amax = fmaxf(amax, __shfl_down(amax, off));
    if ((tid & 63) == 0) redf[tid >> 6] = amax;
    __syncthreads();
    if (tid == 0)
      rowmax[row] = fmaxf(fmaxf(redf[0], redf[1]), fmaxf(redf[2], redf[3]));
  } else {
    const int bid = blockIdx.x - 2048;
    const float4* w4 = (const float4*)w;
    const size_t base = (size_t)bid * 2048;
    double s = 0.0;
#pragma unroll
    for (int i = 0; i < 8; i++) {
      float4 v = w4[base + i * 256 + tid];
      s += (double)((fabsf(v.x) + fabsf(v.y)) + (fabsf(v.z) + fabsf(v.w)));
    }
    for (int off = 32; off; off >>= 1) s += __shfl_down(s, off);
    if ((tid & 63) == 0) red[tid >> 6] = s;
    __syncthreads();
    if (tid == 0) partials[bid] = red[0] + red[1] + red[2] + red[3];
  }
}

// ============================================================================
// K2: single-block scale finalizer -> scales = {a_scale, b_scale, dq}
// ============================================================================
__global__ void scales_kernel(const float* __restrict__ rowmax,
                              const double* __restrict__ partials,
                              float* __restrict__ scales) {
  const int tid = threadIdx.x;
  float m = 0.f;
  double s = 0.0;
#pragma unroll
  for (int i = 0; i < 8; i++) {
    m = fmaxf(m, rowmax[i * 256 + tid]);
    s += partials[i * 256 + tid];
  }
  for (int off = 32; off; off >>= 1) {
    m = fmaxf(m, __shfl_down(m, off));
    s += __shfl_down(s, off);
  }
  __shared__ float redf[4];
  __shared__ double red[4];
  if ((tid & 63) == 0) { redf[tid >> 6] = m; red[tid >> 6] = s; }
  __syncthreads();
  if (tid == 0) {
    float amax = fmaxf(fmaxf(redf[0], redf[1]), fmaxf(redf[2], redf[3]));
    double wsum = red[0] + red[1] + red[2] + red[3];
    float as = 127.0f / fmaxf(amax, 1e-5f);
    float mean_f = (float)(wsum * (1.0 / 16777216.0));
    float bs = 1.0f / fmaxf(mean_f, 1e-5f);
    scales[0] = as;
    scales[1] = bs;
    scales[2] = 1.0f / (as * bs);
  }
}

// ============================================================================
// K3: fused quantizers. blocks [0,2048): A_q rows (int8). blocks [2048,6144):
//     64x64 ternary weight tiles, transposed to Bt[n][k] via padded LDS.
// ============================================================================
__global__ void fused_quant_kernel(const float* __restrict__ x,
                                   const float* __restrict__ rw,
                                   const float* __restrict__ invrms,
                                   const float* __restrict__ scales,
                                   const float* __restrict__ w,
                                   char* __restrict__ Aq,
                                   char* __restrict__ Bt) {
  const int tid = threadIdx.x;
  if (blockIdx.x < 2048) {
    const int row = blockIdx.x;
    const float inv = invrms[row];
    const float as = scales[0];
    const float4* xr = (const float4*)(x + (size_t)row * K_DIM);
    const float4* wr = (const float4*)rw;
    union { char c[16]; int4 v; } o;
#pragma unroll
    for (int i = 0; i < 4; i++) {
      float4 xv = xr[tid * 4 + i];
      float4 wv = wr[tid * 4 + i];
      float t0 = (xv.x * inv) * wv.x;
      float t1 = (xv.y * inv) * wv.y;
      float t2 = (xv.z * inv) * wv.z;
      float t3 = (xv.w * inv) * wv.w;
      o.c[i * 4 + 0] = (char)(int)fminf(fmaxf(rintf(t0 * as), -128.f), 127.f);
      o.c[i * 4 + 1] = (char)(int)fminf(fmaxf(rintf(t1 * as), -128.f), 127.f);
      o.c[i * 4 + 2] = (char)(int)fminf(fmaxf(rintf(t2 * as), -128.f), 127.f);
      o.c[i * 4 + 3] = (char)(int)fminf(fmaxf(rintf(t3 * as), -128.f), 127.f);
    }
    *(int4*)(Aq + (size_t)row * K_DIM + tid * 16) = o.v;
  } else {
    __shared__ float lds[64][68];
    const int tile = blockIdx.x - 2048;
    const int n0 = (tile & 63) * 64;
    const int k0 = (tile >> 6) * 64;
    const float bs = scales[1];
#pragma unroll
    for (int i = 0; i < 4; i++) {
      const int id = i * 256 + tid;
      const int r = id >> 4;
      const int c4 = (id & 15) * 4;
      float4 v = *(const float4*)(w + (size_t)(k0 + r) * N_DIM + n0 + c4);
      lds[c4 + 0][r] = fminf(fmaxf(rintf(v.x * bs), -1.f), 1.f);
      lds[c4 + 1][r] = fminf(fmaxf(rintf(v.y * bs), -1.f), 1.f);
      lds[c4 + 2][r] = fminf(fmaxf(rintf(v.z * bs), -1.f), 1.f);
      lds[c4 + 3][r] = fminf(fmaxf(rintf(v.w * bs), -1.f), 1.f);
    }
    __syncthreads();
    const int rn = tid >> 2;
    const int kg = (tid & 3) * 16;
    union { char c[16]; int4 v; } o;
#pragma unroll
    for (int j = 0; j < 16; j++) o.c[j] = (char)(int)lds[rn][kg + j];
    *(int4*)(Bt + (size_t)(n0 + rn) * K_DIM + k0 + kg) = o.v;
  }
}

// ============================================================================
// K4: i8 GEMM — R4 structure verbatim (best measured): counted-vmcnt free-run
//     pipeline, triple-buffered LDS staged 2 K-tiles ahead, ONE barrier + ONE
//     s_waitcnt vmcnt(6) per K-tile (never 0 in steady state), XOR-swizzle via
//     inverse-swizzled global source + swizzled ds_read, setprio around MFMA.
//     NO explicit lgkmcnt/sched_barrier on the ds_read->MFMA path: the
//     compiler's fine-grained counted lgkmcnt scheduling is near-optimal
//     (hand-pinning it regressed R6-R9, reproducing the m141 lesson).
//     NEW vs R4: XCD band mapping — blocks with flat%8==x all compute brow
//     band x (HW round-robins flat IDs across XCDs), so each XCD's 1MB A
//     panel stays L2-resident for all 32 of its blocks.
//     BM=256 x BN=128 x BK=128, 512 thr / 8 waves (4M x 2N), wave tile 64x64.
// ============================================================================
__global__ void __launch_bounds__(512, 2)
gemm_kernel(const char* __restrict__ Aq, const char* __restrict__ Bt,
            float* __restrict__ out, const float* __restrict__ scales) {
  extern __shared__ char lds[];
  const int tid = threadIdx.x;
  const int lane = tid & 63;
  const int wave = tid >> 6;      // 0..7
  const int wm = wave >> 1;       // 0..3 -> 64-row band
  const int wn = wave & 1;        // 0..1 -> 64-col band
  // XCD band mapping: 256 blocks, flat%8 -> XCD, give each XCD one brow band.
  const int flat = blockIdx.x + blockIdx.y * gridDim.x;
  const int by = flat & 7;        // brow band 0..7  (stays on one XCD)
  const int bx = flat >> 3;       // bcol 0..31
  const int brow = by * BM;
  const int bcol = bx * BN;

  i32x4 acc[4][4];
#pragma unroll
  for (int m = 0; m < 4; m++)
#pragma unroll
    for (int n = 0; n < 4; n++) acc[m][n] = {0, 0, 0, 0};

  // sweep s covers 64 rows (8KB): row = s*64 + wave*8 + (lane>>3), col16 = lane&7.
  // row&7 == lane>>3, so swizzled source col16 = (lane&7) ^ (lane>>3).
  const int sRow8 = lane >> 3;                    // 0..7
  const int srcColB = ((lane & 7) ^ sRow8) * 16;  // inverse-swizzled source byte col

#define STAGE_A(kt, bi, s)                                                        \
  gload_lds16(Aq + (size_t)(brow + (s)*64 + wave * 8 + sRow8) * K_DIM +           \
                  (kt)*BK + srcColB,                                              \
              lds + (bi)*TILE_BYTES + (s)*8192 + wave * 1024 + lane * 16)
#define STAGE_B(kt, bi, s)                                                        \
  gload_lds16(Bt + (size_t)(bcol + (s)*64 + wave * 8 + sRow8) * K_DIM +           \
                  (kt)*BK + srcColB,                                              \
              lds + (bi)*TILE_BYTES + A_TILE_BYTES + (s)*8192 + wave * 1024 +     \
                  lane * 16)

  // prologue: stage tiles 0 and 1 (6 sweeps each; 12 outstanding per wave)
  STAGE_A(0, 0, 0); STAGE_A(0, 0, 1); STAGE_A(0, 0, 2); STAGE_A(0, 0, 3);
  STAGE_B(0, 0, 0); STAGE_B(0, 0, 1);
  STAGE_A(1, 1, 0); STAGE_A(1, 1, 1); STAGE_A(1, 1, 2); STAGE_A(1, 1, 3);
  STAGE_B(1, 1, 0); STAGE_B(1, 1, 1);

  const int frow = lane & 15;
  int bi = 0;
  for (int t = 0; t < KT; ++t) {
    if (t < KT - 1) {
      asm volatile("s_waitcnt vmcnt(6)" ::: "memory");
    } else {
      asm volatile("s_waitcnt vmcnt(0)" ::: "memory");
    }
    __builtin_amdgcn_s_barrier();

    const int si = (bi + 2 >= NBUF) ? bi + 2 - NBUF : bi + 2;
    const bool doStage = (t + 2) < KT;
    const char* bufA = lds + bi * TILE_BYTES;
    const char* bufB = bufA + A_TILE_BYTES;

    if (doStage) {
      STAGE_A(t + 2, si, 0); STAGE_A(t + 2, si, 1); STAGE_A(t + 2, si, 2);
    }
    // ---- kk = 0 ----
    {
      const int sc = ((0 * 4 + (lane >> 4)) ^ (lane & 7)) * 16;  // swizzled col
      i32x4 a[4], b[4];
#pragma unroll
      for (int m = 0; m < 4; m++)
        a[m] = *(const i32x4*)(bufA + (wm * 64 + m * 16 + frow) * BK + sc);
#pragma unroll
      for (int n = 0; n < 4; n++)
        b[n] = *(const i32x4*)(bufB + (wn * 64 + n * 16 + frow) * BK + sc);
      __builtin_amdgcn_s_setprio(1);
#pragma unroll
      for (int m = 0; m < 4; m++)
#pragma unroll
        for (int n = 0; n < 4; n++)
          acc[m][n] = __builtin_amdgcn_mfma_i32_16x16x64_i8(a[m], b[n], acc[m][n], 0, 0, 0);
      __builtin_amdgcn_s_setprio(0);
    }
    if (doStage) {
      STAGE_A(t + 2, si, 3); STAGE_B(t + 2, si, 0); STAGE_B(t + 2, si, 1);
    }
    // ---- kk = 1 ----
    {
      const int sc = ((1 * 4 + (lane >> 4)) ^ (lane & 7)) * 16;
      i32x4 a[4], b[4];
#pragma unroll
      for (int m = 0; m < 4; m++)
        a[m] = *(const i32x4*)(bufA + (wm * 64 + m * 16 + frow) * BK + sc);
#pragma unroll
      for (int n = 0; n < 4; n++)
        b[n] = *(const i32x4*)(bufB + (wn * 64 + n * 16 + frow) * BK + sc);
      __builtin_amdgcn_s_setprio(1);
#pragma unroll
      for (int m = 0; m < 4; m++)
#pragma unroll
        for (int n = 0; n < 4; n++)
          acc[m][n] = __builtin_amdgcn_mfma_i32_16x16x64_i8(a[m], b[n], acc[m][n], 0, 0, 0);
      __builtin_amdgcn_s_setprio(0);
    }
    bi = (bi + 1 >= NBUF) ? 0 : bi + 1;
  }
#undef STAGE_A
#undef STAGE_B

  const float dq = scales[2];
#pragma unroll
  for (int m = 0; m < 4; m++) {
#pragma unroll
    for (int n = 0; n < 4; n++) {
      const int row = wm * 64 + m * 16 + (lane >> 4) * 4;
      const int col = wn * 64 + n * 16 + (lane & 15);
#pragma unroll
      for (int j = 0; j < 4; j++) {
        out[(size_t)(brow + row + j) * N_DIM + bcol + col] = (float)acc[m][n][j] * dq;
      }
    }
  }
}

// ============================================================================
extern "C" void kernel_launch(void* const* d_in, const int* in_sizes, int n_in,
                              void* d_out, int out_size, void* d_ws, size_t ws_size,
                              hipStream_t stream) {
  const float* x      = (const float*)d_in[0];   // [1,2048,4096]
  const float* weight = (const float*)d_in[1];   // [4096,4096]
  const float* rms_w  = (const float*)d_in[2];   // [4096]
  float* out = (float*)d_out;

  uint8_t* ws = (uint8_t*)d_ws;
  float* scales    = (float*)(ws + 0);                     // 3 floats
  float* invrms    = (float*)(ws + 64);                    // 8KB
  float* rowmax    = (float*)(ws + 64 + 8192);             // 8KB
  double* partials = (double*)(ws + 64 + 16384);           // 16KB
  char* Aq = (char*)(ws + 65536);                          // 8MB
  char* Bt = (char*)(ws + 65536 + (size_t)M_DIM * K_DIM);  // 16MB

  (void)hipFuncSetAttribute((const void*)gemm_kernel,
                            hipFuncAttributeMaxDynamicSharedMemorySize, LDS_BYTES);

  fused_reduce_kernel<<<4096, 256, 0, stream>>>(x, rms_w, weight, invrms, rowmax, partials);
  scales_kernel<<<1, 256, 0, stream>>>(rowmax, partials, scales);
  fused_quant_kernel<<<6144, 256, 0, stream>>>(x, rms_w, invrms, scales, weight, Aq, Bt);
  gemm_kernel<<<dim3(N_DIM / BN, M_DIM / BM), 512, LDS_BYTES, stream>>>(Aq, Bt, out, scales);
}

// Round 11
// 74.082 us; speedup vs baseline: 1.0850x; 1.0026x over previous
//
#include <hip/hip_runtime.h>
#include <cstdint>

#define M_DIM 2048
#define K_DIM 4096
#define N_DIM 4096

#define BM 256
#define BN 128
#define BK 128                       // i8 elements = bytes per K-tile row
#define KT (K_DIM / BK)              // 32 K-tiles
#define A_TILE_BYTES (BM * BK)       // 32 KiB
#define B_TILE_BYTES (BN * BK)       // 16 KiB
#define TILE_BYTES (A_TILE_BYTES + B_TILE_BYTES)  // 48 KiB
#define NBUF 3
#define LDS_BYTES (NBUF * TILE_BYTES)             // 144 KiB

typedef __attribute__((ext_vector_type(4))) int i32x4;

__device__ __forceinline__ void gload_lds16(const void* g, void* l) {
  __builtin_amdgcn_global_load_lds(
      (__attribute__((address_space(1))) void*)(g),
      (__attribute__((address_space(3))) void*)(l), 16, 0, 0);
}

// ============================================================================
// K1: fused reducers — no global atomics (single-address device atomics
//     serialize at ~12ns/op; plain per-block stores + tiny second pass win).
//     blocks [0,2048):   per-row RMS -> invrms[row]; per-row absmax of xn
//                        -> rowmax[row] (exclusive slot, plain store).
//     blocks [2048,4096): |W| partial sums -> partials[bid] (double tree).
// ============================================================================
__global__ void fused_reduce_kernel(const float* __restrict__ x,
                                    const float* __restrict__ rw,
                                    const float* __restrict__ w,
                                    float* __restrict__ invrms,
                                    float* __restrict__ rowmax,
                                    double* __restrict__ partials) {
  const int tid = threadIdx.x;
  __shared__ double red[4];
  __shared__ float redf[4];
  __shared__ float sInv;

  if (blockIdx.x < 2048) {
    const int row = blockIdx.x;
    const float4* xr = (const float4*)(x + (size_t)row * K_DIM);
    const float4* wr = (const float4*)rw;
    float4 xv[4];
    double ss = 0.0;
#pragma unroll
    for (int i = 0; i < 4; i++) {
      xv[i] = xr[i * 256 + tid];
      ss += (double)xv[i].x * xv[i].x + (double)xv[i].y * xv[i].y +
            (double)xv[i].z * xv[i].z + (double)xv[i].w * xv[i].w;
    }
    for (int off = 32; off; off >>= 1) ss += __shfl_down(ss, off);
    if ((tid & 63) == 0) red[tid >> 6] = ss;
    __syncthreads();
    if (tid == 0) {
      double t = red[0] + red[1] + red[2] + red[3];
      sInv = (float)(1.0 / sqrt(t * (1.0 / (double)K_DIM) + 1e-6));
    }
    __syncthreads();
    const float inv = sInv;
    if (tid == 0) invrms[row] = inv;

    float amax = 0.f;
#pragma unroll
    for (int i = 0; i < 4; i++) {
      float4 wv = wr[i * 256 + tid];
      amax = fmaxf(amax, fabsf((xv[i].x * inv) * wv.x));
      amax = fmaxf(amax, fabsf((xv[i].y * inv) * wv.y));
      amax = fmaxf(amax, fabsf((xv[i].z * inv) * wv.z));
      amax = fmaxf(amax, fabsf((xv[i].w * inv) * wv.w));
    }
    for (int off = 32; off; off >>= 1) amax = fmaxf(amax, __shfl_down(amax, off));
    if ((tid & 63) == 0) redf[tid >> 6] = amax;
    __syncthreads();
    if (tid == 0)
      rowmax[row] = fmaxf(fmaxf(redf[0], redf[1]), fmaxf(redf[2], redf[3]));
  } else {
    const int bid = blockIdx.x - 2048;
    const float4* w4 = (const float4*)w;
    const size_t base = (size_t)bid * 2048;
    double s = 0.0;
#pragma unroll
    for (int i = 0; i < 8; i++) {
      float4 v = w4[base + i * 256 + tid];
      s += (double)((fabsf(v.x) + fabsf(v.y)) + (fabsf(v.z) + fabsf(v.w)));
    }
    for (int off = 32; off; off >>= 1) s += __shfl_down(s, off);
    if ((tid & 63) == 0) red[tid >> 6] = s;
    __syncthreads();
    if (tid == 0) partials[bid] = red[0] + red[1] + red[2] + red[3];
  }
}

// ============================================================================
// K2: single-block scale finalizer -> scales = {a_scale, b_scale, dq}
// ============================================================================
__global__ void scales_kernel(const float* __restrict__ rowmax,
                              const double* __restrict__ partials,
                              float* __restrict__ scales) {
  const int tid = threadIdx.x;
  float m = 0.f;
  double s = 0.0;
#pragma unroll
  for (int i = 0; i < 8; i++) {
    m = fmaxf(m, rowmax[i * 256 + tid]);
    s += partials[i * 256 + tid];
  }
  for (int off = 32; off; off >>= 1) {
    m = fmaxf(m, __shfl_down(m, off));
    s += __shfl_down(s, off);
  }
  __shared__ float redf[4];
  __shared__ double red[4];
  if ((tid & 63) == 0) { redf[tid >> 6] = m; red[tid >> 6] = s; }
  __syncthreads();
  if (tid == 0) {
    float amax = fmaxf(fmaxf(redf[0], redf[1]), fmaxf(redf[2], redf[3]));
    double wsum = red[0] + red[1] + red[2] + red[3];
    float as = 127.0f / fmaxf(amax, 1e-5f);
    float mean_f = (float)(wsum * (1.0 / 16777216.0));
    float bs = 1.0f / fmaxf(mean_f, 1e-5f);
    scales[0] = as;
    scales[1] = bs;
    scales[2] = 1.0f / (as * bs);
  }
}

// ============================================================================
// K3: fused quantizers. blocks [0,2048): A_q rows (int8), fully coalesced
//     [i*256+tid] indexing (was tid*4+i — 64B/lane stride). blocks
//     [2048,6144): 64x64 ternary weight tiles, transposed to Bt[n][k].
// ============================================================================
__global__ void fused_quant_kernel(const float* __restrict__ x,
                                   const float* __restrict__ rw,
                                   const float* __restrict__ invrms,
                                   const float* __restrict__ scales,
                                   const float* __restrict__ w,
                                   char* __restrict__ Aq,
                                   char* __restrict__ Bt) {
  const int tid = threadIdx.x;
  if (blockIdx.x < 2048) {
    const int row = blockIdx.x;
    const float inv = invrms[row];
    const float as = scales[0];
    const float4* xr = (const float4*)(x + (size_t)row * K_DIM);
    const float4* wr = (const float4*)rw;
    int* Ar = (int*)(Aq + (size_t)row * K_DIM);
#pragma unroll
    for (int i = 0; i < 4; i++) {
      const int idx = i * 256 + tid;      // coalesced: lane-consecutive float4s
      float4 xv = xr[idx];
      float4 wv = wr[idx];
      float t0 = (xv.x * inv) * wv.x;
      float t1 = (xv.y * inv) * wv.y;
      float t2 = (xv.z * inv) * wv.z;
      float t3 = (xv.w * inv) * wv.w;
      union { char c[4]; int v; } o;
      o.c[0] = (char)(int)fminf(fmaxf(rintf(t0 * as), -128.f), 127.f);
      o.c[1] = (char)(int)fminf(fmaxf(rintf(t1 * as), -128.f), 127.f);
      o.c[2] = (char)(int)fminf(fmaxf(rintf(t2 * as), -128.f), 127.f);
      o.c[3] = (char)(int)fminf(fmaxf(rintf(t3 * as), -128.f), 127.f);
      Ar[idx] = o.v;                      // coalesced 4B/lane per pass
    }
  } else {
    __shared__ float lds[64][68];
    const int tile = blockIdx.x - 2048;
    const int n0 = (tile & 63) * 64;
    const int k0 = (tile >> 6) * 64;
    const float bs = scales[1];
#pragma unroll
    for (int i = 0; i < 4; i++) {
      const int id = i * 256 + tid;
      const int r = id >> 4;
      const int c4 = (id & 15) * 4;
      float4 v = *(const float4*)(w + (size_t)(k0 + r) * N_DIM + n0 + c4);
      lds[c4 + 0][r] = fminf(fmaxf(rintf(v.x * bs), -1.f), 1.f);
      lds[c4 + 1][r] = fminf(fmaxf(rintf(v.y * bs), -1.f), 1.f);
      lds[c4 + 2][r] = fminf(fmaxf(rintf(v.z * bs), -1.f), 1.f);
      lds[c4 + 3][r] = fminf(fmaxf(rintf(v.w * bs), -1.f), 1.f);
    }
    __syncthreads();
    const int rn = tid >> 2;
    const int kg = (tid & 3) * 16;
    union { char c[16]; int4 v; } o;
#pragma unroll
    for (int j = 0; j < 16; j++) o.c[j] = (char)(int)lds[rn][kg + j];
    *(int4*)(Bt + (size_t)(n0 + rn) * K_DIM + k0 + kg) = o.v;
  }
}

// ============================================================================
// K4: i8 GEMM — FROZEN at the best-measured structure (R4/R10, ~35-39 us,
//     53% of the 3944 TOPS i8 ubench): counted-vmcnt free-run pipeline,
//     triple-buffered LDS staged 2 K-tiles ahead, ONE barrier + ONE
//     s_waitcnt vmcnt(6) per K-tile (never 0 in steady state), XOR-swizzle
//     via inverse-swizzled global source + swizzled ds_read (0 measured bank
//     conflicts), setprio around MFMA clusters, XCD band mapping.
//     Deliberately NO hand lgkmcnt/sched_barrier on the ds_read->MFMA path:
//     compiler-scheduled counted lgkmcnt is near-optimal; every hand-pinned
//     variant (R6-R9) regressed, reproducing the m141 lesson.
//     Geometry is pinned: M=2048 forces BM*BN <= 256*128 for a full
//     256-block grid; NBUF=3 x 48KB = 144KB excludes 2 blocks/CU.
// ============================================================================
__global__ void __launch_bounds__(512, 2)
gemm_kernel(const char* __restrict__ Aq, const char* __restrict__ Bt,
            float* __restrict__ out, const float* __restrict__ scales) {
  extern __shared__ char lds[];
  const int tid = threadIdx.x;
  const int lane = tid & 63;
  const int wave = tid >> 6;      // 0..7
  const int wm = wave >> 1;       // 0..3 -> 64-row band
  const int wn = wave & 1;        // 0..1 -> 64-col band
  // XCD band mapping: 256 blocks, flat%8 -> XCD, give each XCD one brow band.
  const int flat = blockIdx.x + blockIdx.y * gridDim.x;
  const int by = flat & 7;        // brow band 0..7  (stays on one XCD)
  const int bx = flat >> 3;       // bcol 0..31
  const int brow = by * BM;
  const int bcol = bx * BN;

  i32x4 acc[4][4];
#pragma unroll
  for (int m = 0; m < 4; m++)
#pragma unroll
    for (int n = 0; n < 4; n++) acc[m][n] = {0, 0, 0, 0};

  // sweep s covers 64 rows (8KB): row = s*64 + wave*8 + (lane>>3), col16 = lane&7.
  // row&7 == lane>>3, so swizzled source col16 = (lane&7) ^ (lane>>3).
  const int sRow8 = lane >> 3;                    // 0..7
  const int srcColB = ((lane & 7) ^ sRow8) * 16;  // inverse-swizzled source byte col

#define STAGE_A(kt, bi, s)                                                        \
  gload_lds16(Aq + (size_t)(brow + (s)*64 + wave * 8 + sRow8) * K_DIM +           \
                  (kt)*BK + srcColB,                                              \
              lds + (bi)*TILE_BYTES + (s)*8192 + wave * 1024 + lane * 16)
#define STAGE_B(kt, bi, s)                                                        \
  gload_lds16(Bt + (size_t)(bcol + (s)*64 + wave * 8 + sRow8) * K_DIM +           \
                  (kt)*BK + srcColB,                                              \
              lds + (bi)*TILE_BYTES + A_TILE_BYTES + (s)*8192 + wave * 1024 +     \
                  lane * 16)

  // prologue: stage tiles 0 and 1 (6 sweeps each; 12 outstanding per wave)
  STAGE_A(0, 0, 0); STAGE_A(0, 0, 1); STAGE_A(0, 0, 2); STAGE_A(0, 0, 3);
  STAGE_B(0, 0, 0); STAGE_B(0, 0, 1);
  STAGE_A(1, 1, 0); STAGE_A(1, 1, 1); STAGE_A(1, 1, 2); STAGE_A(1, 1, 3);
  STAGE_B(1, 1, 0); STAGE_B(1, 1, 1);

  const int frow = lane & 15;
  int bi = 0;
  for (int t = 0; t < KT; ++t) {
    if (t < KT - 1) {
      asm volatile("s_waitcnt vmcnt(6)" ::: "memory");
    } else {
      asm volatile("s_waitcnt vmcnt(0)" ::: "memory");
    }
    __builtin_amdgcn_s_barrier();

    const int si = (bi + 2 >= NBUF) ? bi + 2 - NBUF : bi + 2;
    const bool doStage = (t + 2) < KT;
    const char* bufA = lds + bi * TILE_BYTES;
    const char* bufB = bufA + A_TILE_BYTES;

    if (doStage) {
      STAGE_A(t + 2, si, 0); STAGE_A(t + 2, si, 1); STAGE_A(t + 2, si, 2);
    }
    // ---- kk = 0 ----
    {
      const int sc = ((0 * 4 + (lane >> 4)) ^ (lane & 7)) * 16;  // swizzled col
      i32x4 a[4], b[4];
#pragma unroll
      for (int m = 0; m < 4; m++)
        a[m] = *(const i32x4*)(bufA + (wm * 64 + m * 16 + frow) * BK + sc);
#pragma unroll
      for (int n = 0; n < 4; n++)
        b[n] = *(const i32x4*)(bufB + (wn * 64 + n * 16 + frow) * BK + sc);
      __builtin_amdgcn_s_setprio(1);
#pragma unroll
      for (int m = 0; m < 4; m++)
#pragma unroll
        for (int n = 0; n < 4; n++)
          acc[m][n] = __builtin_amdgcn_mfma_i32_16x16x64_i8(a[m], b[n], acc[m][n], 0, 0, 0);
      __builtin_amdgcn_s_setprio(0);
    }
    if (doStage) {
      STAGE_A(t + 2, si, 3); STAGE_B(t + 2, si, 0); STAGE_B(t + 2, si, 1);
    }
    // ---- kk = 1 ----
    {
      const int sc = ((1 * 4 + (lane >> 4)) ^ (lane & 7)) * 16;
      i32x4 a[4], b[4];
#pragma unroll
      for (int m = 0; m < 4; m++)
        a[m] = *(const i32x4*)(bufA + (wm * 64 + m * 16 + frow) * BK + sc);
#pragma unroll
      for (int n = 0; n < 4; n++)
        b[n] = *(const i32x4*)(bufB + (wn * 64 + n * 16 + frow) * BK + sc);
      __builtin_amdgcn_s_setprio(1);
#pragma unroll
      for (int m = 0; m < 4; m++)
#pragma unroll
        for (int n = 0; n < 4; n++)
          acc[m][n] = __builtin_amdgcn_mfma_i32_16x16x64_i8(a[m], b[n], acc[m][n], 0, 0, 0);
      __builtin_amdgcn_s_setprio(0);
    }
    bi = (bi + 1 >= NBUF) ? 0 : bi + 1;
  }
#undef STAGE_A
#undef STAGE_B

  const float dq = scales[2];
#pragma unroll
  for (int m = 0; m < 4; m++) {
#pragma unroll
    for (int n = 0; n < 4; n++) {
      const int row = wm * 64 + m * 16 + (lane >> 4) * 4;
      const int col = wn * 64 + n * 16 + (lane & 15);
#pragma unroll
      for (int j = 0; j < 4; j++) {
        out[(size_t)(brow + row + j) * N_DIM + bcol + col] = (float)acc[m][n][j] * dq;
      }
    }
  }
}

// ============================================================================
extern "C" void kernel_launch(void* const* d_in, const int* in_sizes, int n_in,
                              void* d_out, int out_size, void* d_ws, size_t ws_size,
                              hipStream_t stream) {
  const float* x      = (const float*)d_in[0];   // [1,2048,4096]
  const float* weight = (const float*)d_in[1];   // [4096,4096]
  const float* rms_w  = (const float*)d_in[2];   // [4096]
  float* out = (float*)d_out;

  uint8_t* ws = (uint8_t*)d_ws;
  float* scales    = (float*)(ws + 0);                     // 3 floats
  float* invrms    = (float*)(ws + 64);                    // 8KB
  float* rowmax    = (float*)(ws + 64 + 8192);             // 8KB
  double* partials = (double*)(ws + 64 + 16384);           // 16KB
  char* Aq = (char*)(ws + 65536);                          // 8MB
  char* Bt = (char*)(ws + 65536 + (size_t)M_DIM * K_DIM);  // 16MB

  (void)hipFuncSetAttribute((const void*)gemm_kernel,
                            hipFuncAttributeMaxDynamicSharedMemorySize, LDS_BYTES);

  fused_reduce_kernel<<<4096, 256, 0, stream>>>(x, rms_w, weight, invrms, rowmax, partials);
  scales_kernel<<<1, 256, 0, stream>>>(rowmax, partials, scales);
  fused_quant_kernel<<<6144, 256, 0, stream>>>(x, rms_w, invrms, scales, weight, Aq, Bt);
  gemm_kernel<<<dim3(N_DIM / BN, M_DIM / BM), 512, LDS_BYTES, stream>>>(Aq, Bt, out, scales);
}